// Round 3
// baseline (45.906 us; speedup 1.0000x reference)
//
#include <hip/hip_runtime.h>

#define NB 64
#define NS 512
#define ND 768
#define NT 4
#define NC 10
#define NEG (-1e30f)

// ---------------------------------------------------------------------------
// Kernel 0: materialize W_eff[c][d][t] = sW[d][t] + dA[c][d][t]  (10x3072)
//           and b_eff[c][t] = sb[t] + db[c][t]                    (10x4)
// ---------------------------------------------------------------------------
__global__ void weff_kernel(const float* __restrict__ sW,
                            const float* __restrict__ dA,
                            const float* __restrict__ sb,
                            const float* __restrict__ db,
                            float* __restrict__ weff,
                            float* __restrict__ beff)
{
  const int i = blockIdx.x * 256 + threadIdx.x;
  if (i < NC * ND * NT) weff[i] = sW[i % (ND * NT)] + dA[i];
  if (i < NC * NT)      beff[i] = sb[i & 3] + db[i];
}

// ---------------------------------------------------------------------------
// Kernel 1: token-per-lane projection + log_softmax.
// 512 blocks x 64 threads; global token g = blockIdx*64 + lane, b = g>>9.
// Weights are wave-uniform (corpus uniform per block) -> SGPR s_loads;
// embedding row streamed as float4 per lane (L1 absorbs the 4x line reuse).
// ---------------------------------------------------------------------------
__global__ __launch_bounds__(64) void logits_kernel(
    const int* __restrict__ words, const int* __restrict__ corpus,
    const float* __restrict__ embed, const float* __restrict__ weff,
    const float* __restrict__ beff, float* __restrict__ logits)
{
  const int lane = threadIdx.x;
  const int g = blockIdx.x * 64 + lane;
  const int b = g >> 9;
  const int c = __builtin_amdgcn_readfirstlane(corpus[b]);
  const float* __restrict__ w = weff + c * (ND * NT);

  const int word = words[g];
  const float* __restrict__ row = embed + (size_t)word * ND;

  float a0 = 0.f, a1 = 0.f, a2 = 0.f, a3 = 0.f;
#pragma unroll 2
  for (int d0 = 0; d0 < ND; d0 += 16) {
    float xs[16];
    *(float4*)(xs + 0)  = *(const float4*)(row + d0 + 0);
    *(float4*)(xs + 4)  = *(const float4*)(row + d0 + 4);
    *(float4*)(xs + 8)  = *(const float4*)(row + d0 + 8);
    *(float4*)(xs + 12) = *(const float4*)(row + d0 + 12);
    const float* __restrict__ wc = w + d0 * NT;
#pragma unroll
    for (int q = 0; q < 16; ++q) {
      a0 = fmaf(xs[q], wc[q * 4 + 0], a0);
      a1 = fmaf(xs[q], wc[q * 4 + 1], a1);
      a2 = fmaf(xs[q], wc[q * 4 + 2], a2);
      a3 = fmaf(xs[q], wc[q * 4 + 3], a3);
    }
  }

  const float* __restrict__ be = beff + c * NT;
  a0 += be[0]; a1 += be[1]; a2 += be[2]; a3 += be[3];
  const float m = fmaxf(fmaxf(a0, a1), fmaxf(a2, a3));
  const float sum = __expf(a0 - m) + __expf(a1 - m) + __expf(a2 - m) + __expf(a3 - m);
  const float lse = m + __logf(sum);
  ((float4*)logits)[g] = make_float4(a0 - lse, a1 - lse, a2 - lse, a3 - lse);
}

// ---------------------------------------------------------------------------
// Kernel 2: CRF via chunk-parallel log-semiring scan + fused gold score.
// (unchanged from round 2 — passed with absmax 0.0)
// ---------------------------------------------------------------------------
__global__ __launch_bounds__(256) void crf_kernel(
    const int* __restrict__ words, const int* __restrict__ target,
    const float* __restrict__ trans, const float* __restrict__ start_s,
    const float* __restrict__ end_s, const float* __restrict__ logits,
    float* __restrict__ out)
{
  const int tid = threadIdx.x;
  const int b = blockIdx.x;
  const int c = tid >> 2;   // chunk 0..63
  const int a = tid & 3;    // basis row

  __shared__ float bufA[64][16];
  __shared__ float bufB[32][16];
  __shared__ float wg[4];
  __shared__ int   wc[4];

  const float* lg = logits + (size_t)b * NS * NT;
  const int* wb = words + b * NS;
  const int* tb = target + b * NS;

  // ---- gold partials: positions 2*tid, 2*tid+1 ----
  float gp = 0.f; int cp = 0;
#pragma unroll
  for (int q = 0; q < 2; ++q) {
    const int s = tid * 2 + q;
    if (wb[s] != 0) {
      const int t = tb[s];
      gp += lg[s * 4 + t];
      if (s > 0) gp += trans[tb[s - 1] * 4 + t];
      ++cp;
    }
  }
#pragma unroll
  for (int off = 32; off; off >>= 1) {
    gp += __shfl_xor(gp, off);
    cp += __shfl_xor(cp, off);
  }
  if ((tid & 63) == 0) { wg[tid >> 6] = gp; wc[tid >> 6] = cp; }

  // ---- phase A: chunk recursion ----
  float T[4][4];
#pragma unroll
  for (int i = 0; i < 4; ++i)
#pragma unroll
    for (int j = 0; j < 4; ++j) T[i][j] = trans[i * 4 + j];

  const int s_beg = 1 + c * 8;   // chunks cover s = 1..511
  float4 lv[8]; int wm[8];
#pragma unroll
  for (int q = 0; q < 8; ++q) {
    const int s = s_beg + q;
    const bool in = s < NS;
    wm[q] = in ? wb[s] : 0;
    lv[q] = in ? *(const float4*)(lg + s * 4) : make_float4(0.f, 0.f, 0.f, 0.f);
  }

  float v0 = (a == 0) ? 0.f : NEG;
  float v1 = (a == 1) ? 0.f : NEG;
  float v2 = (a == 2) ? 0.f : NEG;
  float v3 = (a == 3) ? 0.f : NEG;
#pragma unroll
  for (int q = 0; q < 8; ++q) {
    if (wm[q] != 0) {
      const float4 l = lv[q];
      float t0, t1, t2, t3, m, sm;
      float n0, n1, n2, n3;
      t0 = v0 + T[0][0]; t1 = v1 + T[1][0]; t2 = v2 + T[2][0]; t3 = v3 + T[3][0];
      m = fmaxf(fmaxf(t0, t1), fmaxf(t2, t3));
      sm = __expf(t0 - m) + __expf(t1 - m) + __expf(t2 - m) + __expf(t3 - m);
      n0 = m + __logf(sm) + l.x;
      t0 = v0 + T[0][1]; t1 = v1 + T[1][1]; t2 = v2 + T[2][1]; t3 = v3 + T[3][1];
      m = fmaxf(fmaxf(t0, t1), fmaxf(t2, t3));
      sm = __expf(t0 - m) + __expf(t1 - m) + __expf(t2 - m) + __expf(t3 - m);
      n1 = m + __logf(sm) + l.y;
      t0 = v0 + T[0][2]; t1 = v1 + T[1][2]; t2 = v2 + T[2][2]; t3 = v3 + T[3][2];
      m = fmaxf(fmaxf(t0, t1), fmaxf(t2, t3));
      sm = __expf(t0 - m) + __expf(t1 - m) + __expf(t2 - m) + __expf(t3 - m);
      n2 = m + __logf(sm) + l.z;
      t0 = v0 + T[0][3]; t1 = v1 + T[1][3]; t2 = v2 + T[2][3]; t3 = v3 + T[3][3];
      m = fmaxf(fmaxf(t0, t1), fmaxf(t2, t3));
      sm = __expf(t0 - m) + __expf(t1 - m) + __expf(t2 - m) + __expf(t3 - m);
      n3 = m + __logf(sm) + l.w;
      v0 = n0; v1 = n1; v2 = n2; v3 = n3;
    }
  }
  bufA[c][a * 4 + 0] = v0;
  bufA[c][a * 4 + 1] = v1;
  bufA[c][a * 4 + 2] = v2;
  bufA[c][a * 4 + 3] = v3;

  // ---- phase B: pairwise tree composition (6 levels) ----
  float* src = &bufA[0][0];
  float* dst = &bufB[0][0];
  for (int n = 64; n > 1; n >>= 1) {
    const int entries = (n >> 1) * 16;
    __syncthreads();
    for (int e = tid; e < entries; e += 256) {
      const int p = e >> 4;
      const int aa = (e >> 2) & 3;
      const int jj = e & 3;
      const float* C1 = src + (2 * p) * 16;
      const float* C2 = src + (2 * p + 1) * 16;
      const float t0 = C1[aa * 4 + 0] + C2[0 * 4 + jj];
      const float t1 = C1[aa * 4 + 1] + C2[1 * 4 + jj];
      const float t2 = C1[aa * 4 + 2] + C2[2 * 4 + jj];
      const float t3 = C1[aa * 4 + 3] + C2[3 * 4 + jj];
      const float m = fmaxf(fmaxf(t0, t1), fmaxf(t2, t3));
      dst[p * 16 + aa * 4 + jj] =
          m + __logf(__expf(t0 - m) + __expf(t1 - m) + __expf(t2 - m) + __expf(t3 - m));
    }
    float* tmp = src; src = dst; dst = tmp;
  }
  __syncthreads();

  if (tid == 0) {
    const float* C = &bufA[0][0];
    const float4 l0 = *(const float4*)lg;
    const float a0 = l0.x + start_s[0];
    const float a1 = l0.y + start_s[1];
    const float a2 = l0.z + start_s[2];
    const float a3 = l0.w + start_s[3];
    float af[4];
#pragma unroll
    for (int j = 0; j < 4; ++j) {
      const float t0 = a0 + C[0 * 4 + j];
      const float t1 = a1 + C[1 * 4 + j];
      const float t2 = a2 + C[2 * 4 + j];
      const float t3 = a3 + C[3 * 4 + j];
      const float m = fmaxf(fmaxf(t0, t1), fmaxf(t2, t3));
      af[j] = m + __logf(__expf(t0 - m) + __expf(t1 - m) + __expf(t2 - m) + __expf(t3 - m));
    }
    const float z0 = af[0] + end_s[0], z1 = af[1] + end_s[1];
    const float z2 = af[2] + end_s[2], z3 = af[3] + end_s[3];
    const float mz = fmaxf(fmaxf(z0, z1), fmaxf(z2, z3));
    const float norm = mz + __logf(__expf(z0 - mz) + __expf(z1 - mz) +
                                   __expf(z2 - mz) + __expf(z3 - mz));

    float gold = wg[0] + wg[1] + wg[2] + wg[3];
    const int cnt = wc[0] + wc[1] + wc[2] + wc[3];
    const int last = (cnt - 1) > 0 ? (cnt - 1) : 0;
    gold += start_s[tb[0]] + end_s[tb[last]];
    out[b] = norm - gold;
  }
}

extern "C" void kernel_launch(void* const* d_in, const int* in_sizes, int n_in,
                              void* d_out, int out_size, void* d_ws, size_t ws_size,
                              hipStream_t stream) {
  const int*   words   = (const int*)d_in[0];
  const int*   target  = (const int*)d_in[1];
  const int*   corpus  = (const int*)d_in[2];
  const float* embed   = (const float*)d_in[3];
  const float* sW      = (const float*)d_in[4];
  const float* sb      = (const float*)d_in[5];
  const float* dA      = (const float*)d_in[6];
  const float* db      = (const float*)d_in[7];
  const float* trans   = (const float*)d_in[8];
  const float* start_s = (const float*)d_in[9];
  const float* end_s   = (const float*)d_in[10];
  float* out = (float*)d_out;

  float* logits = (float*)d_ws;                    // NB*NS*NT = 131072 floats
  float* weff   = logits + (size_t)NB * NS * NT;   // 10*3072 floats
  float* beff   = weff + NC * ND * NT;             // 10*4 floats

  weff_kernel<<<(NC * ND * NT + 255) / 256, 256, 0, stream>>>(sW, dA, sb, db, weff, beff);
  logits_kernel<<<(NB * NS) / 64, 64, 0, stream>>>(words, corpus, embed, weff, beff, logits);
  crf_kernel<<<NB, 256, 0, stream>>>(words, target, trans, start_s, end_s, logits, out);
}